// Round 6
// baseline (670.908 us; speedup 1.0000x reference)
//
#include <hip/hip_runtime.h>
#include <hip/hip_bf16.h>

// GCN 2-layer for MI355X. Structure exploited from reference:
//   tgt = repeat(arange(N), DEG)  ->  pool[n] = sum_{j<16} ft[nbr[16n+j]]
//   z = [ft+pool, ft*pool] (128);  out = relu(z @ W^T) (64);  final: L2-normalize.
// Output dtype = reference output dtype = FLOAT32 (rounds 1-2 failed by writing
// bf16 into a float buffer: top half stayed zero -> absmax == max|ref| == stub).
// One wave per node, lane = feature/output index.

#define N_NODES 50000
#define DEG 16
#define DIM 64

// W [64][128] row-major staged into LDS transposed+grouped:
//   Wq[(k>>2)*256 + o*4 + (k&3)] = W[o][k]
// -> lane o reads a contiguous float4 per k-group: conflict-free ds_read_b128.

__global__ void gcn_layer1(const float* __restrict__ ft, const float* __restrict__ W,
                           const int* __restrict__ nbr, float* __restrict__ out) {
  __shared__ float Wq[8192];
  const int tid = threadIdx.x;
  for (int i = tid; i < 8192; i += 256) {
    const int o = i >> 7;
    const int k = i & 127;
    Wq[((k >> 2) << 8) + (o << 2) + (k & 3)] = W[i];
  }
  __syncthreads();

  const int lane = tid & 63;
  const int wid  = tid >> 6;
  const int step = gridDim.x * 4;

  for (int n = blockIdx.x * 4 + wid; n < N_NODES; n += step) {
    const float node = ft[n * DIM + lane];

    const int* nb = nbr + n * DEG;
    float s0 = 0.f, s1 = 0.f, s2 = 0.f, s3 = 0.f;
#pragma unroll
    for (int j = 0; j < DEG; j += 4) {
      s0 += ft[nb[j + 0] * DIM + lane];
      s1 += ft[nb[j + 1] * DIM + lane];
      s2 += ft[nb[j + 2] * DIM + lane];
      s3 += ft[nb[j + 3] * DIM + lane];
    }
    const float pool = (s0 + s1) + (s2 + s3);

    const float z1 = node + pool;   // z[k], k=0..63, held in lane k
    const float z2 = node * pool;   // z[64+k]

    float a0 = 0.f, a1 = 0.f, a2 = 0.f, a3 = 0.f;
#pragma unroll
    for (int g = 0; g < 16; ++g) {
      const float4 w = *reinterpret_cast<const float4*>(&Wq[(g << 8) + (lane << 2)]);
      a0 = fmaf(__shfl(z1, 4 * g + 0, 64), w.x, a0);
      a1 = fmaf(__shfl(z1, 4 * g + 1, 64), w.y, a1);
      a2 = fmaf(__shfl(z1, 4 * g + 2, 64), w.z, a2);
      a3 = fmaf(__shfl(z1, 4 * g + 3, 64), w.w, a3);
    }
#pragma unroll
    for (int g = 0; g < 16; ++g) {
      const float4 w = *reinterpret_cast<const float4*>(&Wq[((16 + g) << 8) + (lane << 2)]);
      a0 = fmaf(__shfl(z2, 4 * g + 0, 64), w.x, a0);
      a1 = fmaf(__shfl(z2, 4 * g + 1, 64), w.y, a1);
      a2 = fmaf(__shfl(z2, 4 * g + 2, 64), w.z, a2);
      a3 = fmaf(__shfl(z2, 4 * g + 3, 64), w.w, a3);
    }
    out[n * DIM + lane] = fmaxf((a0 + a1) + (a2 + a3), 0.f);
  }
}

__global__ void gcn_layer2(const float* __restrict__ ft, const float* __restrict__ W,
                           const int* __restrict__ nbr, float* __restrict__ out) {
  __shared__ float Wq[8192];
  const int tid = threadIdx.x;
  for (int i = tid; i < 8192; i += 256) {
    const int o = i >> 7;
    const int k = i & 127;
    Wq[((k >> 2) << 8) + (o << 2) + (k & 3)] = W[i];
  }
  __syncthreads();

  const int lane = tid & 63;
  const int wid  = tid >> 6;
  const int step = gridDim.x * 4;

  for (int n = blockIdx.x * 4 + wid; n < N_NODES; n += step) {
    const float node = ft[n * DIM + lane];

    const int* nb = nbr + n * DEG;
    float s0 = 0.f, s1 = 0.f, s2 = 0.f, s3 = 0.f;
#pragma unroll
    for (int j = 0; j < DEG; j += 4) {
      s0 += ft[nb[j + 0] * DIM + lane];
      s1 += ft[nb[j + 1] * DIM + lane];
      s2 += ft[nb[j + 2] * DIM + lane];
      s3 += ft[nb[j + 3] * DIM + lane];
    }
    const float pool = (s0 + s1) + (s2 + s3);

    const float z1 = node + pool;
    const float z2 = node * pool;

    float a0 = 0.f, a1 = 0.f, a2 = 0.f, a3 = 0.f;
#pragma unroll
    for (int g = 0; g < 16; ++g) {
      const float4 w = *reinterpret_cast<const float4*>(&Wq[(g << 8) + (lane << 2)]);
      a0 = fmaf(__shfl(z1, 4 * g + 0, 64), w.x, a0);
      a1 = fmaf(__shfl(z1, 4 * g + 1, 64), w.y, a1);
      a2 = fmaf(__shfl(z1, 4 * g + 2, 64), w.z, a2);
      a3 = fmaf(__shfl(z1, 4 * g + 3, 64), w.w, a3);
    }
#pragma unroll
    for (int g = 0; g < 16; ++g) {
      const float4 w = *reinterpret_cast<const float4*>(&Wq[((16 + g) << 8) + (lane << 2)]);
      a0 = fmaf(__shfl(z2, 4 * g + 0, 64), w.x, a0);
      a1 = fmaf(__shfl(z2, 4 * g + 1, 64), w.y, a1);
      a2 = fmaf(__shfl(z2, 4 * g + 2, 64), w.z, a2);
      a3 = fmaf(__shfl(z2, 4 * g + 3, 64), w.w, a3);
    }
    const float v = fmaxf((a0 + a1) + (a2 + a3), 0.f);

    // L2-normalize across the 64 lanes of this row
    float s = v * v;
    s += __shfl_xor(s, 32, 64);
    s += __shfl_xor(s, 16, 64);
    s += __shfl_xor(s, 8, 64);
    s += __shfl_xor(s, 4, 64);
    s += __shfl_xor(s, 2, 64);
    s += __shfl_xor(s, 1, 64);
    out[n * DIM + lane] = v / fmaxf(sqrtf(s), 1e-12f);
  }
}

extern "C" void kernel_launch(void* const* d_in, const int* in_sizes, int n_in,
                              void* d_out, int out_size, void* d_ws, size_t ws_size,
                              hipStream_t stream) {
  // Insertion order: ft_lv0 (3.2M), W1 (8192), W2 (8192), nbr (800K), tgt (800K).
  // Guard against alphabetical ordering via in_sizes.
  const float* ft0;
  const float* W1;
  const float* W2;
  const int*   nbr;
  if (in_sizes[0] == N_NODES * DIM) {          // insertion order
    ft0 = (const float*)d_in[0];
    W1  = (const float*)d_in[1];
    W2  = (const float*)d_in[2];
    nbr = (const int*)d_in[3];
  } else {                                      // alphabetical fallback
    W1  = (const float*)d_in[0];
    W2  = (const float*)d_in[1];
    ft0 = (const float*)d_in[2];
    nbr = (const int*)d_in[3];
  }

  float* ft1 = (float*)d_ws;                    // N*DIM f32 = 12.8 MB scratch
  float* out = (float*)d_out;                   // N*DIM f32 (reference dtype)

  dim3 block(256), grid(1024);
  gcn_layer1<<<grid, block, 0, stream>>>(ft0, W1, nbr, ft1);
  gcn_layer2<<<grid, block, 0, stream>>>(ft1, W2, nbr, out);
}

// Round 7
// 171.594 us; speedup vs baseline: 3.9098x; 3.9098x over previous
//
#include <hip/hip_runtime.h>
#include <hip/hip_bf16.h>

// GCN 2-layer, MI355X. Round-6 baseline passed (671us) but was memory-stall
// bound: VALUBusy 7%, 890MB L2-fill per layer (random gather thrashing the
// 4MiB/XCD L2 with a 12.8MB f32 table). This round: bf16 gather tables
// (half traffic, table ~ L2-sized) + occupancy 45->~90% (16KB bf16 W in LDS,
// grid 2048) + replace 128 shfl-bpermutes/node with wave-uniform broadcast
// ds_read_b128 of a per-wave z buffer.

#define N_NODES 50000
#define DEG 16
#define DIM 64

__device__ __forceinline__ unsigned short f2b(float f) {  // RNE f32->bf16
  unsigned int u = __float_as_uint(f);
  u = (u + 0x7FFFu + ((u >> 16) & 1u)) >> 16;
  return (unsigned short)u;
}
__device__ __forceinline__ float b2f(unsigned short h) {
  return __uint_as_float(((unsigned int)h) << 16);
}

__global__ void cast_bf16(const float* __restrict__ in, unsigned short* __restrict__ out, int n4) {
  const int i = blockIdx.x * 256 + threadIdx.x;
  if (i < n4) {
    const float4 v = reinterpret_cast<const float4*>(in)[i];
    ushort4 o4;
    o4.x = f2b(v.x); o4.y = f2b(v.y); o4.z = f2b(v.z); o4.w = f2b(v.w);
    reinterpret_cast<ushort4*>(out)[i] = o4;
  }
}

// W [64][128] row-major f32 -> LDS packed bf16: Wb[(k>>2)*64 + o] = W[o][4k..4k+3]
// lane o reads ushort4 (8B, ds_read_b64, 2-way bank alias = free).
// z (128 f32) staged per-wave in LDS; matmul reads it with wave-uniform
// ds_read_b128 (broadcast, conflict-free). No barriers in the node loop.

__global__ void gcn_layer1(const unsigned short* __restrict__ ftb, const float* __restrict__ W,
                           const int* __restrict__ nbr, unsigned short* __restrict__ outb) {
  __shared__ ushort4 Wb[2048];      // 16 KB
  __shared__ float zb[4][128];      // 2 KB
  const int tid = threadIdx.x;
  for (int e = tid; e < 2048; e += 256) {
    const int g = e >> 6, o = e & 63;
    const float4 s = *reinterpret_cast<const float4*>(W + o * 128 + g * 4);
    ushort4 p;
    p.x = f2b(s.x); p.y = f2b(s.y); p.z = f2b(s.z); p.w = f2b(s.w);
    Wb[e] = p;
  }
  __syncthreads();

  const int lane = tid & 63, wid = tid >> 6;
  const int step = gridDim.x * 4;

  for (int n = blockIdx.x * 4 + wid; n < N_NODES; n += step) {
    const float node = b2f(ftb[n * DIM + lane]);

    const int4* nb4 = reinterpret_cast<const int4*>(nbr + n * DEG);
    const int4 A = nb4[0], B = nb4[1], C = nb4[2], D = nb4[3];
    float s0 = b2f(ftb[A.x * DIM + lane]) + b2f(ftb[A.y * DIM + lane]);
    float s1 = b2f(ftb[A.z * DIM + lane]) + b2f(ftb[A.w * DIM + lane]);
    float s2 = b2f(ftb[B.x * DIM + lane]) + b2f(ftb[B.y * DIM + lane]);
    float s3 = b2f(ftb[B.z * DIM + lane]) + b2f(ftb[B.w * DIM + lane]);
    s0 += b2f(ftb[C.x * DIM + lane]) + b2f(ftb[C.y * DIM + lane]);
    s1 += b2f(ftb[C.z * DIM + lane]) + b2f(ftb[C.w * DIM + lane]);
    s2 += b2f(ftb[D.x * DIM + lane]) + b2f(ftb[D.y * DIM + lane]);
    s3 += b2f(ftb[D.z * DIM + lane]) + b2f(ftb[D.w * DIM + lane]);
    const float pool = (s0 + s1) + (s2 + s3);

    zb[wid][lane]      = node + pool;   // z[0..63]
    zb[wid][64 + lane] = node * pool;   // z[64..127]

    float a0 = 0.f, a1 = 0.f, a2 = 0.f, a3 = 0.f;
#pragma unroll
    for (int g = 0; g < 32; ++g) {
      const float4 zq = *reinterpret_cast<const float4*>(&zb[wid][g * 4]); // uniform -> broadcast
      const ushort4 wp = Wb[(g << 6) + lane];
      a0 = fmaf(zq.x, b2f(wp.x), a0);
      a1 = fmaf(zq.y, b2f(wp.y), a1);
      a2 = fmaf(zq.z, b2f(wp.z), a2);
      a3 = fmaf(zq.w, b2f(wp.w), a3);
    }
    outb[n * DIM + lane] = f2b(fmaxf((a0 + a1) + (a2 + a3), 0.f));
  }
}

__global__ void gcn_layer2(const unsigned short* __restrict__ ftb, const float* __restrict__ W,
                           const int* __restrict__ nbr, float* __restrict__ out) {
  __shared__ ushort4 Wb[2048];
  __shared__ float zb[4][128];
  const int tid = threadIdx.x;
  for (int e = tid; e < 2048; e += 256) {
    const int g = e >> 6, o = e & 63;
    const float4 s = *reinterpret_cast<const float4*>(W + o * 128 + g * 4);
    ushort4 p;
    p.x = f2b(s.x); p.y = f2b(s.y); p.z = f2b(s.z); p.w = f2b(s.w);
    Wb[e] = p;
  }
  __syncthreads();

  const int lane = tid & 63, wid = tid >> 6;
  const int step = gridDim.x * 4;

  for (int n = blockIdx.x * 4 + wid; n < N_NODES; n += step) {
    const float node = b2f(ftb[n * DIM + lane]);

    const int4* nb4 = reinterpret_cast<const int4*>(nbr + n * DEG);
    const int4 A = nb4[0], B = nb4[1], C = nb4[2], D = nb4[3];
    float s0 = b2f(ftb[A.x * DIM + lane]) + b2f(ftb[A.y * DIM + lane]);
    float s1 = b2f(ftb[A.z * DIM + lane]) + b2f(ftb[A.w * DIM + lane]);
    float s2 = b2f(ftb[B.x * DIM + lane]) + b2f(ftb[B.y * DIM + lane]);
    float s3 = b2f(ftb[B.z * DIM + lane]) + b2f(ftb[B.w * DIM + lane]);
    s0 += b2f(ftb[C.x * DIM + lane]) + b2f(ftb[C.y * DIM + lane]);
    s1 += b2f(ftb[C.z * DIM + lane]) + b2f(ftb[C.w * DIM + lane]);
    s2 += b2f(ftb[D.x * DIM + lane]) + b2f(ftb[D.y * DIM + lane]);
    s3 += b2f(ftb[D.z * DIM + lane]) + b2f(ftb[D.w * DIM + lane]);
    const float pool = (s0 + s1) + (s2 + s3);

    zb[wid][lane]      = node + pool;
    zb[wid][64 + lane] = node * pool;

    float a0 = 0.f, a1 = 0.f, a2 = 0.f, a3 = 0.f;
#pragma unroll
    for (int g = 0; g < 32; ++g) {
      const float4 zq = *reinterpret_cast<const float4*>(&zb[wid][g * 4]);
      const ushort4 wp = Wb[(g << 6) + lane];
      a0 = fmaf(zq.x, b2f(wp.x), a0);
      a1 = fmaf(zq.y, b2f(wp.y), a1);
      a2 = fmaf(zq.z, b2f(wp.z), a2);
      a3 = fmaf(zq.w, b2f(wp.w), a3);
    }
    const float v = fmaxf((a0 + a1) + (a2 + a3), 0.f);

    float s = v * v;
    s += __shfl_xor(s, 32, 64);
    s += __shfl_xor(s, 16, 64);
    s += __shfl_xor(s, 8, 64);
    s += __shfl_xor(s, 4, 64);
    s += __shfl_xor(s, 2, 64);
    s += __shfl_xor(s, 1, 64);
    out[n * DIM + lane] = v / fmaxf(sqrtf(s), 1e-12f);
  }
}

extern "C" void kernel_launch(void* const* d_in, const int* in_sizes, int n_in,
                              void* d_out, int out_size, void* d_ws, size_t ws_size,
                              hipStream_t stream) {
  const float* ft0;
  const float* W1;
  const float* W2;
  const int*   nbr;
  if (in_sizes[0] == N_NODES * DIM) {          // insertion order
    ft0 = (const float*)d_in[0];
    W1  = (const float*)d_in[1];
    W2  = (const float*)d_in[2];
    nbr = (const int*)d_in[3];
  } else {                                      // alphabetical fallback
    W1  = (const float*)d_in[0];
    W2  = (const float*)d_in[1];
    ft0 = (const float*)d_in[2];
    nbr = (const int*)d_in[3];
  }

  unsigned short* ftb0 = (unsigned short*)d_ws;          // 6.4 MB bf16 ft_lv0
  unsigned short* ft1b = ftb0 + (size_t)N_NODES * DIM;   // 6.4 MB bf16 ft_lv1
  float* out = (float*)d_out;

  const int n4 = (N_NODES * DIM) / 4;                    // 800k float4s
  cast_bf16<<<dim3((n4 + 255) / 256), dim3(256), 0, stream>>>(ft0, ftb0, n4);

  dim3 block(256), grid(2048);
  gcn_layer1<<<grid, block, 0, stream>>>(ftb0, W1, nbr, ft1b);
  gcn_layer2<<<grid, block, 0, stream>>>(ft1b, W2, nbr, out);
}